// Round 5
// baseline (2485.471 us; speedup 1.0000x reference)
//
#include <hip/hip_runtime.h>
#include <cstdint>
#include <cstddef>

#define NN 100000
#define NE 3200000
#define D 128

#define NBUK  1563          // ceil(NN/64): bucket = 64-node dst range
#define NBUKP 1792          // padded to 256*7 for scan convenience
#define BCAP  2560          // per-bucket capacity (mean 2048, +11 sigma)
#define EPB   12800         // edges per partition block (250 blocks)

typedef __attribute__((ext_vector_type(8))) short bf16x8;
typedef __attribute__((ext_vector_type(4))) float f32x4;

__device__ __forceinline__ unsigned short f2bf(float f) {
    unsigned int u = __float_as_uint(f);
    u += 0x7FFFu + ((u >> 16) & 1u);          // round-to-nearest-even
    return (unsigned short)(u >> 16);
}
__device__ __forceinline__ float bflo(unsigned int v) { return __uint_as_float(v << 16); }
__device__ __forceinline__ float bfhi(unsigned int v) { return __uint_as_float(v & 0xFFFF0000u); }

// ---------------------------------------------------------------------------
// x (fp32) -> x_bf16. 12.8M elems, 8 per thread.
// ---------------------------------------------------------------------------
__global__ __launch_bounds__(256)
void k_convert(const float* __restrict__ x, unsigned short* __restrict__ xb)
{
    const size_t i8 = ((size_t)blockIdx.x * 256 + threadIdx.x) * 8;
    const float4 v0 = *reinterpret_cast<const float4*>(x + i8);
    const float4 v1 = *reinterpret_cast<const float4*>(x + i8 + 4);
    uint4 o;
    o.x = (unsigned)f2bf(v0.x) | ((unsigned)f2bf(v0.y) << 16);
    o.y = (unsigned)f2bf(v0.z) | ((unsigned)f2bf(v0.w) << 16);
    o.z = (unsigned)f2bf(v1.x) | ((unsigned)f2bf(v1.y) << 16);
    o.w = (unsigned)f2bf(v1.z) | ((unsigned)f2bf(v1.w) << 16);
    *reinterpret_cast<uint4*>(xb + i8) = o;
}

// ---------------------------------------------------------------------------
// Single-pass 1563-way radix partition with LDS staging + burst flush.
// Block owns EPB=12800 edges. Pass 2a: LDS histogram. Scan in LDS -> inclusive
// ends. Pass 2b: re-read edges (L2-hot), backward-fill staging via atomicSub
// (ends become starts). Flush: each thread walks a contiguous 50-word window,
// bucket pointer advances monotonically (sorted starts), per-run global
// cursor atomic + contiguous burst write -> full-line writebacks.
// Edge word: (dst & 63) << 17 | src  (17-bit src, 6-bit local dst).
// ---------------------------------------------------------------------------
__global__ __launch_bounds__(256)
void k_partition(const int* __restrict__ ei,
                 unsigned int* __restrict__ gcur,
                 unsigned int* __restrict__ ebuf)
{
    __shared__ unsigned int staging[EPB];      // 51200 B
    __shared__ unsigned int hist[NBUKP];       // 7168 B (counts->ends->starts)
    __shared__ unsigned int partials[256];     // 1024 B

    const int t  = threadIdx.x;
    const int e0 = blockIdx.x * EPB;

    // zero histogram
    #pragma unroll
    for (int k = 0; k < 7; ++k) hist[t * 7 + k] = 0u;
    __syncthreads();

    // pass 2a: histogram (dst only)
    for (int j = 0; j < 50; ++j) {
        const int d = ei[NE + e0 + j * 256 + t];
        atomicAdd(&hist[d >> 6], 1u);
    }
    __syncthreads();

    // scan: per-thread sum of 7 contiguous -> block scan -> inclusive ends
    unsigned int c = 0;
    #pragma unroll
    for (int k = 0; k < 7; ++k) c += hist[t * 7 + k];
    partials[t] = c;
    __syncthreads();
    for (int dstep = 1; dstep < 256; dstep <<= 1) {
        const unsigned int v = (t >= dstep) ? partials[t - dstep] : 0u;
        __syncthreads();
        partials[t] += v;
        __syncthreads();
    }
    unsigned int running = (t == 0) ? 0u : partials[t - 1];
    #pragma unroll
    for (int k = 0; k < 7; ++k) {
        running += hist[t * 7 + k];
        hist[t * 7 + k] = running;            // inclusive end
    }
    __syncthreads();

    // pass 2b: backward-fill staging; hist becomes starts
    for (int j = 0; j < 50; ++j) {
        const int e = e0 + j * 256 + t;
        const int s = ei[e];
        const int d = ei[NE + e];
        const int b = d >> 6;
        const unsigned int pos = atomicSub(&hist[b], 1u) - 1u;
        staging[pos] = ((unsigned)(d & 63) << 17) | (unsigned)s;
    }
    __syncthreads();

    // flush: thread window [t*50, t*50+50), monotone bucket walk
    int i = t * 50;
    const int wEnd = i + 50;
    int lo = 0, hi = NBUKP - 1;
    while (lo < hi) {                          // largest b with start[b] <= i
        const int mid = (lo + hi + 1) >> 1;
        if ((int)hist[mid] <= i) lo = mid; else hi = mid - 1;
    }
    int bp = lo;
    while (i < wEnd) {
        while (bp + 1 < NBUKP && (int)hist[bp + 1] <= i) ++bp;
        const int bEnd = (bp + 1 < NBUKP) ? (int)hist[bp + 1] : EPB;
        const int runEnd = (wEnd < bEnd) ? wEnd : bEnd;
        const int len = runEnd - i;
        const unsigned int g = atomicAdd(&gcur[bp], (unsigned)len);
        if (g + (unsigned)len <= (unsigned)BCAP) {
            for (int k = 0; k < len; ++k)
                ebuf[(size_t)bp * BCAP + g + k] = staging[i + k];
        }
        i = runEnd;
    }
}

// ---------------------------------------------------------------------------
// Pack W' = [Wl; Wr] (256x128) into bf16 MFMA B-fragment layout (verified r4).
// ---------------------------------------------------------------------------
__global__ __launch_bounds__(256)
void k_wprep(const float* __restrict__ Wl, const float* __restrict__ Wr,
             unsigned short* __restrict__ wf)
{
    const int tid  = blockIdx.x * 256 + threadIdx.x;   // 32768 total
    const int j    = tid & 7;
    const int lane = (tid >> 3) & 63;
    const int tt   = (tid >> 9) & 7;
    const int kt   = tid >> 12;
    const int k    = kt * 32 + (lane >> 4) * 8 + j;
    const int cc   = tt * 16 + (lane & 15);
    const float v  = (k < D) ? Wl[k * D + cc] : Wr[(k - D) * D + cc];
    wf[tid] = f2bf(v);
}

// ---------------------------------------------------------------------------
// Per-bucket fused kernel: edge gather -> LDS f32 accumulate (ds_add_f32,
// no-return => no dep chain) -> mean(bf16) -> MFMA GEMM [mean|x]@[Wl;Wr]+b
// -> LayerNorm -> exact GELU. Block = bucket = 64 nodes, 4 waves.
// LDS 50.4 KB -> 3 blocks/CU.
// ---------------------------------------------------------------------------
__global__ __launch_bounds__(256)
void k_bucket(const unsigned short* __restrict__ xb,
              const unsigned int* __restrict__ gcur,
              const unsigned int* __restrict__ ebuf,
              const unsigned short* __restrict__ wf,
              const float* __restrict__ bl,
              const float* __restrict__ gamma,
              const float* __restrict__ beta,
              float* __restrict__ out)
{
    __shared__ float acc[64][D];               // 32768 B
    __shared__ unsigned short smean[64][136];  // 17408 B (stride 272 = 17*16)
    __shared__ unsigned int degL[64];

    const int t    = threadIdx.x;
    const int w    = t >> 6;
    const int lane = t & 63;
    const int b    = blockIdx.x;
    const int nodeBase = b * 64;

    // zero accumulators
    #pragma unroll
    for (int k = 0; k < 8; ++k)
        reinterpret_cast<float4*>(acc)[t * 8 + k] = make_float4(0.f, 0.f, 0.f, 0.f);
    if (t < 64) degL[t] = 0u;
    __syncthreads();

    // ---- phase 2: gather-accumulate this bucket's edges ----
    unsigned int cnt = gcur[b];
    const int count = (int)(cnt < (unsigned)BCAP ? cnt : (unsigned)BCAP);
    const size_t bb = (size_t)b * BCAP;

    for (int cb = w * 64; cb < count; cb += 256) {
        const int m = (count - cb < 64) ? (count - cb) : 64;
        const unsigned int word = (lane < m) ? ebuf[bb + cb + lane] : 0u;
        int j = 0;
        for (; j + 4 <= m; j += 4) {
            const unsigned int w0 = __shfl(word, j + 0);
            const unsigned int w1 = __shfl(word, j + 1);
            const unsigned int w2 = __shfl(word, j + 2);
            const unsigned int w3 = __shfl(word, j + 3);
            const unsigned int x0 = *reinterpret_cast<const unsigned int*>(
                xb + ((size_t)(w0 & 0x1FFFFu) << 7) + (lane << 1));
            const unsigned int x1 = *reinterpret_cast<const unsigned int*>(
                xb + ((size_t)(w1 & 0x1FFFFu) << 7) + (lane << 1));
            const unsigned int x2 = *reinterpret_cast<const unsigned int*>(
                xb + ((size_t)(w2 & 0x1FFFFu) << 7) + (lane << 1));
            const unsigned int x3 = *reinterpret_cast<const unsigned int*>(
                xb + ((size_t)(w3 & 0x1FFFFu) << 7) + (lane << 1));
            atomicAdd(&acc[w0 >> 17][lane * 2 + 0], bflo(x0));
            atomicAdd(&acc[w0 >> 17][lane * 2 + 1], bfhi(x0));
            atomicAdd(&acc[w1 >> 17][lane * 2 + 0], bflo(x1));
            atomicAdd(&acc[w1 >> 17][lane * 2 + 1], bfhi(x1));
            atomicAdd(&acc[w2 >> 17][lane * 2 + 0], bflo(x2));
            atomicAdd(&acc[w2 >> 17][lane * 2 + 1], bfhi(x2));
            atomicAdd(&acc[w3 >> 17][lane * 2 + 0], bflo(x3));
            atomicAdd(&acc[w3 >> 17][lane * 2 + 1], bfhi(x3));
            if (lane == 0) {
                atomicAdd(&degL[w0 >> 17], 1u);
                atomicAdd(&degL[w1 >> 17], 1u);
                atomicAdd(&degL[w2 >> 17], 1u);
                atomicAdd(&degL[w3 >> 17], 1u);
            }
        }
        for (; j < m; ++j) {
            const unsigned int w0 = __shfl(word, j);
            const unsigned int x0 = *reinterpret_cast<const unsigned int*>(
                xb + ((size_t)(w0 & 0x1FFFFu) << 7) + (lane << 1));
            atomicAdd(&acc[w0 >> 17][lane * 2 + 0], bflo(x0));
            atomicAdd(&acc[w0 >> 17][lane * 2 + 1], bfhi(x0));
            if (lane == 0) atomicAdd(&degL[w0 >> 17], 1u);
        }
    }
    __syncthreads();

    // ---- phase 3: mean -> smean (bf16) ----
    {
        const int n  = t >> 2;
        const int d0 = (t & 3) << 5;
        const unsigned int dg = degL[n];
        const float inv = 1.0f / (float)(dg > 1u ? dg : 1u);
        for (int dd = 0; dd < 32; dd += 2) {
            const float v0 = acc[n][d0 + dd] * inv;
            const float v1 = acc[n][d0 + dd + 1] * inv;
            *reinterpret_cast<unsigned int*>(&smean[n][d0 + dd]) =
                (unsigned)f2bf(v0) | ((unsigned)f2bf(v1) << 16);
        }
    }
    __syncthreads();

    // ---- phase 4: MFMA GEMM, K = 256 = [mean(128) | x(128)] (verified r4) ----
    const int row  = lane & 15;
    const int kgrp = lane >> 4;
    const int node_r = nodeBase + w * 16 + row;
    const size_t xrow = (size_t)(node_r < NN ? node_r : NN - 1) << 7;

    f32x4 accr[8];
    const f32x4 zero = {0.f, 0.f, 0.f, 0.f};
    #pragma unroll
    for (int q = 0; q < 8; ++q) accr[q] = zero;

    #pragma unroll
    for (int kt = 0; kt < 8; ++kt) {
        bf16x8 a;
        if (kt < 4) {
            a = *reinterpret_cast<const bf16x8*>(&smean[w * 16 + row][kt * 32 + kgrp * 8]);
        } else {
            a = *reinterpret_cast<const bf16x8*>(xb + xrow + (kt - 4) * 32 + kgrp * 8);
        }
        #pragma unroll
        for (int q = 0; q < 8; ++q) {
            const bf16x8 bfrag = *reinterpret_cast<const bf16x8*>(
                wf + (((kt * 8 + q) * 64 + lane) << 3));
            accr[q] = __builtin_amdgcn_mfma_f32_16x16x32_bf16(a, bfrag, accr[q], 0, 0, 0);
        }
    }

    // ---- phase 5: bias + LayerNorm + exact GELU + store ----
    const int col = lane & 15;
    float gv[8], bev[8], blv[8];
    #pragma unroll
    for (int q = 0; q < 8; ++q) {
        gv[q]  = gamma[q * 16 + col];
        bev[q] = beta[q * 16 + col];
        blv[q] = bl[q * 16 + col];
    }
    const float k2 = 0.70710678118654752f;
    #pragma unroll
    for (int r = 0; r < 4; ++r) {
        float p = 0.f, p2 = 0.f;
        #pragma unroll
        for (int q = 0; q < 8; ++q) {
            const float h = accr[q][r] + blv[q];
            p += h; p2 += h * h;
        }
        #pragma unroll
        for (int m = 1; m <= 8; m <<= 1) {
            p  += __shfl_xor(p,  m, 64);
            p2 += __shfl_xor(p2, m, 64);
        }
        const float mu   = p * (1.0f / 128.0f);
        const float var  = p2 * (1.0f / 128.0f) - mu * mu;
        const float rstd = rsqrtf(var + 1e-5f);
        const int node = nodeBase + w * 16 + kgrp * 4 + r;
        if (node < NN) {
            #pragma unroll
            for (int q = 0; q < 8; ++q) {
                const float h = accr[q][r] + blv[q];
                const float y = (h - mu) * rstd * gv[q] + bev[q];
                out[(size_t)node * D + q * 16 + col] = 0.5f * y * (1.0f + erff(y * k2));
            }
        }
    }
}

extern "C" void kernel_launch(void* const* d_in, const int* in_sizes, int n_in,
                              void* d_out, int out_size, void* d_ws, size_t ws_size,
                              hipStream_t stream)
{
    const float* x     = (const float*)d_in[0];
    const int*   ei    = (const int*)d_in[1];
    const float* Wl    = (const float*)d_in[2];
    const float* bl    = (const float*)d_in[3];
    const float* Wr    = (const float*)d_in[4];
    const float* gamma = (const float*)d_in[5];
    const float* beta  = (const float*)d_in[6];
    float* out = (float*)d_out;

    // ws layout (~42.1 MB; 51.6 MB proven available in round 1):
    //   gcur  [NBUKP u32]           @ 0        (7.2 KB, memset each launch)
    //   ebuf  [1600*BCAP u32]       @ 32768    (16.4 MB)
    //   xb    [NN*D u16]            @ 16416768 (25.6 MB)
    //   wf    [256*128 u16]         @ 42016768 (64 KB)
    char* wsp = (char*)d_ws;
    unsigned int*   gcur = (unsigned int*)(wsp + 0);
    unsigned int*   ebuf = (unsigned int*)(wsp + 32768);
    unsigned short* xb   = (unsigned short*)(wsp + 16416768);
    unsigned short* wf   = (unsigned short*)(wsp + 42016768);

    hipMemsetAsync(gcur, 0, NBUKP * sizeof(unsigned int), stream);

    k_convert<<<6250, 256, 0, stream>>>(x, xb);          // NN*D/8/256
    k_partition<<<NE / EPB, 256, 0, stream>>>(ei, gcur, ebuf);   // 250 blocks
    k_wprep<<<128, 256, 0, stream>>>(Wl, Wr, wf);
    k_bucket<<<NBUK, 256, 0, stream>>>(xb, gcur, ebuf, wf, bl, gamma, beta, out);
}

// Round 6
// 256.750 us; speedup vs baseline: 9.6805x; 9.6805x over previous
//
#include <hip/hip_runtime.h>
#include <cstdint>
#include <cstddef>

#define NN 100000
#define NE 3200000
#define D 128

#define NBUK  1563          // ceil(NN/64): bucket = 64-node dst range
#define NBUKP 1792          // padded to 256*7 for partition scan
#define BCAP  2560          // per-bucket capacity (mean 2048, +11 sigma)
#define EPB   12800         // edges per partition block (250 blocks)

typedef __attribute__((ext_vector_type(8))) short bf16x8;
typedef __attribute__((ext_vector_type(4))) float f32x4;

__device__ __forceinline__ unsigned short f2bf(float f) {
    unsigned int u = __float_as_uint(f);
    u += 0x7FFFu + ((u >> 16) & 1u);          // round-to-nearest-even
    return (unsigned short)(u >> 16);
}
__device__ __forceinline__ float bflo(unsigned int v) { return __uint_as_float(v << 16); }
__device__ __forceinline__ float bfhi(unsigned int v) { return __uint_as_float(v & 0xFFFF0000u); }

// ---------------------------------------------------------------------------
// x (fp32) -> x_bf16. 12.8M elems, 8 per thread.
// ---------------------------------------------------------------------------
__global__ __launch_bounds__(256)
void k_convert(const float* __restrict__ x, unsigned short* __restrict__ xb)
{
    const size_t i8 = ((size_t)blockIdx.x * 256 + threadIdx.x) * 8;
    const float4 v0 = *reinterpret_cast<const float4*>(x + i8);
    const float4 v1 = *reinterpret_cast<const float4*>(x + i8 + 4);
    uint4 o;
    o.x = (unsigned)f2bf(v0.x) | ((unsigned)f2bf(v0.y) << 16);
    o.y = (unsigned)f2bf(v0.z) | ((unsigned)f2bf(v0.w) << 16);
    o.z = (unsigned)f2bf(v1.x) | ((unsigned)f2bf(v1.y) << 16);
    o.w = (unsigned)f2bf(v1.z) | ((unsigned)f2bf(v1.w) << 16);
    *reinterpret_cast<uint4*>(xb + i8) = o;
}

// ---------------------------------------------------------------------------
// Single-pass 1563-way radix partition (unchanged from r5 — ~50 us, burst
// flush keeps write-amp low). Edge word: (dst & 63) << 17 | src.
// ---------------------------------------------------------------------------
__global__ __launch_bounds__(256)
void k_partition(const int* __restrict__ ei,
                 unsigned int* __restrict__ gcur,
                 unsigned int* __restrict__ ebuf)
{
    __shared__ unsigned int staging[EPB];      // 51200 B
    __shared__ unsigned int hist[NBUKP];       // 7168 B
    __shared__ unsigned int partials[256];

    const int t  = threadIdx.x;
    const int e0 = blockIdx.x * EPB;

    #pragma unroll
    for (int k = 0; k < 7; ++k) hist[t * 7 + k] = 0u;
    __syncthreads();

    for (int j = 0; j < 50; ++j) {
        const int d = ei[NE + e0 + j * 256 + t];
        atomicAdd(&hist[d >> 6], 1u);
    }
    __syncthreads();

    unsigned int c = 0;
    #pragma unroll
    for (int k = 0; k < 7; ++k) c += hist[t * 7 + k];
    partials[t] = c;
    __syncthreads();
    for (int dstep = 1; dstep < 256; dstep <<= 1) {
        const unsigned int v = (t >= dstep) ? partials[t - dstep] : 0u;
        __syncthreads();
        partials[t] += v;
        __syncthreads();
    }
    unsigned int running = (t == 0) ? 0u : partials[t - 1];
    #pragma unroll
    for (int k = 0; k < 7; ++k) {
        running += hist[t * 7 + k];
        hist[t * 7 + k] = running;            // inclusive end
    }
    __syncthreads();

    for (int j = 0; j < 50; ++j) {
        const int e = e0 + j * 256 + t;
        const int s = ei[e];
        const int d = ei[NE + e];
        const int b = d >> 6;
        const unsigned int pos = atomicSub(&hist[b], 1u) - 1u;
        staging[pos] = ((unsigned)(d & 63) << 17) | (unsigned)s;
    }
    __syncthreads();

    int i = t * 50;
    const int wEnd = i + 50;
    int lo = 0, hi = NBUKP - 1;
    while (lo < hi) {
        const int mid = (lo + hi + 1) >> 1;
        if ((int)hist[mid] <= i) lo = mid; else hi = mid - 1;
    }
    int bp = lo;
    while (i < wEnd) {
        while (bp + 1 < NBUKP && (int)hist[bp + 1] <= i) ++bp;
        const int bEnd = (bp + 1 < NBUKP) ? (int)hist[bp + 1] : EPB;
        const int runEnd = (wEnd < bEnd) ? wEnd : bEnd;
        const int len = runEnd - i;
        const unsigned int g = atomicAdd(&gcur[bp], (unsigned)len);
        if (g + (unsigned)len <= (unsigned)BCAP) {
            for (int k = 0; k < len; ++k)
                ebuf[(size_t)bp * BCAP + g + k] = staging[i + k];
        }
        i = runEnd;
    }
}

// ---------------------------------------------------------------------------
// Pack W' = [Wl; Wr] (256x128) into bf16 MFMA B-fragment layout (verified r4).
// ---------------------------------------------------------------------------
__global__ __launch_bounds__(256)
void k_wprep(const float* __restrict__ Wl, const float* __restrict__ Wr,
             unsigned short* __restrict__ wf)
{
    const int tid  = blockIdx.x * 256 + threadIdx.x;   // 32768 total
    const int j    = tid & 7;
    const int lane = (tid >> 3) & 63;
    const int tt   = (tid >> 9) & 7;
    const int kt   = tid >> 12;
    const int k    = kt * 32 + (lane >> 4) * 8 + j;
    const int cc   = tt * 16 + (lane & 15);
    const float v  = (k < D) ? Wl[k * D + cc] : Wr[(k - D) * D + cc];
    wf[tid] = f2bf(v);
}

// ---------------------------------------------------------------------------
// Per-bucket fused kernel, v2 (atomic-free feature path):
//  A. register-stage this bucket's <=2560 edge words (10/thread)
//  B. LDS counting sort by local dst (one 4B LDS atomic per EDGE, not per
//     feature) -> per-node contiguous segments in ew[], starts in hstart[]
//  C. per-wave gather: wave w owns nodes w*16..+15; segment words read at
//     wave-uniform LDS addresses (HW broadcast), neighbor rows (256B bf16)
//     accumulated in VGPR f32 (2 feats/lane), 4-deep unrolled for MLP
//  D. mean -> smean bf16 -> MFMA GEMM [mean|x]@[Wl;Wr]+b -> LN -> GELU (r4)
// LDS ~28.2 KB -> 5 blocks/CU.
// ---------------------------------------------------------------------------
__global__ __launch_bounds__(256)
void k_bucket(const unsigned short* __restrict__ xb,
              const unsigned int* __restrict__ gcur,
              const unsigned int* __restrict__ ebuf,
              const unsigned short* __restrict__ wf,
              const float* __restrict__ bl,
              const float* __restrict__ gamma,
              const float* __restrict__ beta,
              float* __restrict__ out)
{
    __shared__ unsigned int ew[BCAP];          // 10240 B sorted edge words
    __shared__ unsigned int hcnt[64];          // counts -> scatter cursors
    __shared__ unsigned int hstart[65];        // segment starts
    __shared__ unsigned short smean[64][136];  // 17408 B (stride 272B)

    const int t    = threadIdx.x;
    const int w    = t >> 6;
    const int lane = t & 63;
    const int b    = blockIdx.x;
    const int nodeBase = b * 64;

    const unsigned int cntu = gcur[b];
    const int count = (int)(cntu < (unsigned)BCAP ? cntu : (unsigned)BCAP);
    const size_t bb = (size_t)b * BCAP;

    // A: register-stage + zero histogram
    unsigned int wreg[10];
    #pragma unroll
    for (int k = 0; k < 10; ++k) {
        const int i = t + k * 256;
        wreg[k] = (i < count) ? ebuf[bb + i] : 0xFFFFFFFFu;
    }
    if (t < 64) hcnt[t] = 0u;
    __syncthreads();

    // B1: histogram (one LDS atomic per edge)
    #pragma unroll
    for (int k = 0; k < 10; ++k)
        if (wreg[k] != 0xFFFFFFFFu) atomicAdd(&hcnt[wreg[k] >> 17], 1u);
    __syncthreads();

    // B2: wave-0 inclusive scan of 64 counts -> hstart[1..64], hstart[0]=0
    if (t < 64) {
        unsigned int p = hcnt[t];
        #pragma unroll
        for (int d = 1; d < 64; d <<= 1) {
            const unsigned int v = __shfl_up(p, d, 64);
            if (lane >= d) p += v;
        }
        hstart[t + 1] = p;
        if (t == 0) hstart[0] = 0u;
    }
    __syncthreads();
    if (t < 64) hcnt[t] = hstart[t];          // cursors = starts
    __syncthreads();

    // B3: scatter into sorted ew[]
    #pragma unroll
    for (int k = 0; k < 10; ++k) {
        const unsigned int wv = wreg[k];
        if (wv != 0xFFFFFFFFu) {
            const unsigned int pos = atomicAdd(&hcnt[wv >> 17], 1u);
            ew[pos] = wv;
        }
    }
    __syncthreads();

    // C: per-wave gather, VGPR accumulation (lane holds feats 2*lane, 2*lane+1)
    for (int i = 0; i < 16; ++i) {
        const int n = w * 16 + i;
        const int s = (int)hstart[n];
        const int e = (int)hstart[n + 1];
        const int dg = e - s;
        float ax = 0.f, ay = 0.f;
        int c = s;
        for (; c + 4 <= e; c += 4) {
            const unsigned int w0 = ew[c + 0];   // uniform addr -> broadcast
            const unsigned int w1 = ew[c + 1];
            const unsigned int w2 = ew[c + 2];
            const unsigned int w3 = ew[c + 3];
            const unsigned int x0 = *reinterpret_cast<const unsigned int*>(
                xb + ((size_t)(w0 & 0x1FFFFu) << 7) + (lane << 1));
            const unsigned int x1 = *reinterpret_cast<const unsigned int*>(
                xb + ((size_t)(w1 & 0x1FFFFu) << 7) + (lane << 1));
            const unsigned int x2 = *reinterpret_cast<const unsigned int*>(
                xb + ((size_t)(w2 & 0x1FFFFu) << 7) + (lane << 1));
            const unsigned int x3 = *reinterpret_cast<const unsigned int*>(
                xb + ((size_t)(w3 & 0x1FFFFu) << 7) + (lane << 1));
            ax += bflo(x0) + bflo(x1) + bflo(x2) + bflo(x3);
            ay += bfhi(x0) + bfhi(x1) + bfhi(x2) + bfhi(x3);
        }
        for (; c < e; ++c) {
            const unsigned int w0 = ew[c];
            const unsigned int x0 = *reinterpret_cast<const unsigned int*>(
                xb + ((size_t)(w0 & 0x1FFFFu) << 7) + (lane << 1));
            ax += bflo(x0); ay += bfhi(x0);
        }
        const float inv = 1.0f / (float)(dg > 1 ? dg : 1);
        *reinterpret_cast<unsigned int*>(&smean[n][lane << 1]) =
            (unsigned)f2bf(ax * inv) | ((unsigned)f2bf(ay * inv) << 16);
    }
    __syncthreads();

    // D: MFMA GEMM, K = 256 = [mean(128) | x(128)] (verified r4)
    const int row  = lane & 15;
    const int kgrp = lane >> 4;
    const int node_r = nodeBase + w * 16 + row;
    const size_t xrow = (size_t)(node_r < NN ? node_r : NN - 1) << 7;

    f32x4 accr[8];
    const f32x4 zero = {0.f, 0.f, 0.f, 0.f};
    #pragma unroll
    for (int q = 0; q < 8; ++q) accr[q] = zero;

    #pragma unroll
    for (int kt = 0; kt < 8; ++kt) {
        bf16x8 a;
        if (kt < 4) {
            a = *reinterpret_cast<const bf16x8*>(&smean[w * 16 + row][kt * 32 + kgrp * 8]);
        } else {
            a = *reinterpret_cast<const bf16x8*>(xb + xrow + (kt - 4) * 32 + kgrp * 8);
        }
        #pragma unroll
        for (int q = 0; q < 8; ++q) {
            const bf16x8 bfrag = *reinterpret_cast<const bf16x8*>(
                wf + (((kt * 8 + q) * 64 + lane) << 3));
            accr[q] = __builtin_amdgcn_mfma_f32_16x16x32_bf16(a, bfrag, accr[q], 0, 0, 0);
        }
    }

    // bias + LayerNorm + exact GELU + store
    const int col = lane & 15;
    float gv[8], bev[8], blv[8];
    #pragma unroll
    for (int q = 0; q < 8; ++q) {
        gv[q]  = gamma[q * 16 + col];
        bev[q] = beta[q * 16 + col];
        blv[q] = bl[q * 16 + col];
    }
    const float k2 = 0.70710678118654752f;
    #pragma unroll
    for (int r = 0; r < 4; ++r) {
        float p = 0.f, p2 = 0.f;
        #pragma unroll
        for (int q = 0; q < 8; ++q) {
            const float h = accr[q][r] + blv[q];
            p += h; p2 += h * h;
        }
        #pragma unroll
        for (int m = 1; m <= 8; m <<= 1) {
            p  += __shfl_xor(p,  m, 64);
            p2 += __shfl_xor(p2, m, 64);
        }
        const float mu   = p * (1.0f / 128.0f);
        const float var  = p2 * (1.0f / 128.0f) - mu * mu;
        const float rstd = rsqrtf(var + 1e-5f);
        const int node = nodeBase + w * 16 + kgrp * 4 + r;
        if (node < NN) {
            #pragma unroll
            for (int q = 0; q < 8; ++q) {
                const float h = accr[q][r] + blv[q];
                const float y = (h - mu) * rstd * gv[q] + bev[q];
                out[(size_t)node * D + q * 16 + col] = 0.5f * y * (1.0f + erff(y * k2));
            }
        }
    }
}

extern "C" void kernel_launch(void* const* d_in, const int* in_sizes, int n_in,
                              void* d_out, int out_size, void* d_ws, size_t ws_size,
                              hipStream_t stream)
{
    const float* x     = (const float*)d_in[0];
    const int*   ei    = (const int*)d_in[1];
    const float* Wl    = (const float*)d_in[2];
    const float* bl    = (const float*)d_in[3];
    const float* Wr    = (const float*)d_in[4];
    const float* gamma = (const float*)d_in[5];
    const float* beta  = (const float*)d_in[6];
    float* out = (float*)d_out;

    // ws layout (~42.1 MB; 51.6 MB proven available in round 1):
    //   gcur [NBUKP u32] @ 0 | ebuf [1600*BCAP u32] @ 32768 |
    //   xb [NN*D u16] @ 16416768 | wf [256*128 u16] @ 42016768
    char* wsp = (char*)d_ws;
    unsigned int*   gcur = (unsigned int*)(wsp + 0);
    unsigned int*   ebuf = (unsigned int*)(wsp + 32768);
    unsigned short* xb   = (unsigned short*)(wsp + 16416768);
    unsigned short* wf   = (unsigned short*)(wsp + 42016768);

    hipMemsetAsync(gcur, 0, NBUKP * sizeof(unsigned int), stream);

    k_convert<<<6250, 256, 0, stream>>>(x, xb);
    k_partition<<<NE / EPB, 256, 0, stream>>>(ei, gcur, ebuf);
    k_wprep<<<128, 256, 0, stream>>>(Wl, Wr, wf);
    k_bucket<<<NBUK, 256, 0, stream>>>(xb, gcur, ebuf, wf, bl, gamma, beta, out);
}